// Round 6
// baseline (92.214 us; speedup 1.0000x reference)
//
#include <hip/hip_runtime.h>

#define Bb 64
#define Ll 32
#define Hh 128
#define Oo 16384
#define Cc 32
#define TOo 64
#define NT 1024

__device__ __forceinline__ float rdlane(float v, int l) {
    return __int_as_float(__builtin_amdgcn_readlane(__float_as_int(v), l));
}

// ---------------------------------------------------------------------------
// prep: A[b,h] = relu(z@Wz+bz) @ W1[:H]   (b1 folded into G)
//       SA2w[b] = sum_h 0.5*W2[h]*A[b,h]
// ---------------------------------------------------------------------------
__global__ __launch_bounds__(256) void prep_kernel(
    const float* __restrict__ z, const float* __restrict__ Wz,
    const float* __restrict__ bz, const float* __restrict__ W1,
    const float* __restrict__ W2,
    float* __restrict__ A, float* __restrict__ SA2w)
{
    __shared__ float pz[2][Hh];
    __shared__ float ps[2][Hh];
    const int t  = threadIdx.x;
    const int h  = t & (Hh - 1);
    const int bb = t >> 7;
    const int b  = blockIdx.x * 2 + bb;

    float v = bz[h];
#pragma unroll
    for (int c = 0; c < Ll; ++c)
        v = fmaf(z[b * Ll + c], Wz[c * Hh + h], v);
    pz[bb][h] = fmaxf(v, 0.f);
    __syncthreads();

    float a = 0.f;
#pragma unroll
    for (int k = 0; k < Hh; ++k)
        a = fmaf(pz[bb][k], W1[k * Hh + h], a);
    A[b * Hh + h] = a;
    ps[bb][h] = 0.5f * W2[h] * a;
    __syncthreads();

    if (h == 0) {
        float s = 0.f;
        for (int k = 0; k < Hh; ++k) s += ps[bb][k];
        SA2w[b] = s;
    }
}

// ---------------------------------------------------------------------------
// main: out[b,o] = SA2w[b] + b2 + sum_h w2h[h]*g[o,h] + sum_h w2h[h]*|A[b,h]+g[o,h]|
//   w2h = 0.5*W2  (w*relu(x) = 0.5*w*x + 0.5*w*|x|, exact)
// 1024 threads = 16 waves: 4 h-slices x 4 b-groups. lane = o.
// ALL wave-uniform operands delivered via v_readlane from per-lane staged
// registers (VALU pipe) -- zero broadcast LDS/VMEM reads in hot loops.
// ---------------------------------------------------------------------------
__global__ __launch_bounds__(NT) void main_kernel(
    const float* __restrict__ A,  const float* __restrict__ SA2w,
    const float* __restrict__ fe, const float* __restrict__ fb,
    const float* __restrict__ W1, const float* __restrict__ b1,
    const float* __restrict__ W2, const float* __restrict__ b2,
    float* __restrict__ out)
{
    __shared__ float gT[Hh][TOo + 1];      // 33.3 KB, stride-65: rotated banks
    __shared__ float part[4][Bb][TOo];     // 64 KB

    const int t    = threadIdx.x;
    const int o0   = blockIdx.x * TOo;
    const int lane = t & 63;
    const int wave = __builtin_amdgcn_readfirstlane(t >> 6);

    // inner-phase wave roles
    const int hh = wave & 3, bg = wave >> 2;
    const int h0 = hh * 32,  b0 = bg * 16;

    // ---- stage per-lane A slice: lane = bi*4 + hc, 32B each (L2-hot) ----
    const int bi_l = lane >> 2, hc_l = lane & 3;
    const float* Ap = A + (b0 + bi_l) * Hh + h0 + hc_l * 8;
    const float4 av_lo = *(const float4*)(Ap);
    const float4 av_hi = *(const float4*)(Ap + 4);

    // ---- G phase: per-wave og = wave>>1 (8 o), per-lane h = (wave&1)*64+lane
    {
        const int hG = ((wave & 1) << 6) + lane;   // 0..127
        const int og = wave >> 1;                  // 0..7
        // per-lane fe stage: 64 lanes = 8 o x 8 c-chunks (coalesced 128B rows)
        const int ol = lane >> 3, ccl = lane & 7;
        const float4 fe4 = *(const float4*)(fe + (o0 + og * 8 + ol) * Cc + ccl * 4);

        float w1f[Cc];
#pragma unroll
        for (int c = 0; c < Cc; ++c)
            w1f[c] = W1[(Hh + c) * Hh + hG];       // coalesced, L2-hot
        const float w1b = W1[(Hh + Cc) * Hh + hG];
        const float b1h = b1[hG];

#pragma unroll
        for (int j = 0; j < 8; ++j) {
            float g = fmaf(fb[o0 + og * 8 + j], w1b, b1h);
#pragma unroll
            for (int c2 = 0; c2 < 8; ++c2) {
                const int L = j * 8 + c2;          // compile-time constant
                g = fmaf(rdlane(fe4.x, L), w1f[c2 * 4 + 0], g);
                g = fmaf(rdlane(fe4.y, L), w1f[c2 * 4 + 1], g);
                g = fmaf(rdlane(fe4.z, L), w1f[c2 * 4 + 2], g);
                g = fmaf(rdlane(fe4.w, L), w1f[c2 * 4 + 3], g);
            }
            gT[hG][og * 8 + j] = g;                // (65*lane+c)%32: conflict-free
        }
    }
    __syncthreads();

    // ---- per-lane operands for inner loop ----
    float gv[32];
#pragma unroll
    for (int k = 0; k < 32; ++k)
        gv[k] = gT[h0 + k][lane];                  // stride-65: conflict-free

    const float w2l = 0.5f * W2[h0 + (lane & 31)]; // per-lane, coalesced
    float w2v[32];
#pragma unroll
    for (int k = 0; k < 32; ++k)
        w2v[k] = rdlane(w2l, k);

    float sg = 0.f;
#pragma unroll
    for (int k = 0; k < 32; ++k)
        sg = fmaf(w2v[k], gv[k], sg);

    float acc[16];
#pragma unroll
    for (int bi = 0; bi < 16; ++bi) acc[bi] = sg;

    // ---- inner loop: pure VALU, A via readlane (no memory ops) ----
#pragma unroll
    for (int jc = 0; jc < 8; ++jc) {
        const float4 a4s = (jc & 1) ? av_hi : av_lo;    // compile-time select
        const float g0 = gv[4 * jc + 0], g1 = gv[4 * jc + 1];
        const float g2 = gv[4 * jc + 2], g3 = gv[4 * jc + 3];
        const float u0 = w2v[4 * jc + 0], u1 = w2v[4 * jc + 1];
        const float u2 = w2v[4 * jc + 2], u3 = w2v[4 * jc + 3];
#pragma unroll
        for (int bi = 0; bi < 16; ++bi) {
            const int L = bi * 4 + (jc >> 1);           // compile-time constant
            acc[bi] = fmaf(__builtin_fabsf(rdlane(a4s.x, L) + g0), u0, acc[bi]);
            acc[bi] = fmaf(__builtin_fabsf(rdlane(a4s.y, L) + g1), u1, acc[bi]);
            acc[bi] = fmaf(__builtin_fabsf(rdlane(a4s.z, L) + g2), u2, acc[bi]);
            acc[bi] = fmaf(__builtin_fabsf(rdlane(a4s.w, L) + g3), u3, acc[bi]);
        }
    }

#pragma unroll
    for (int bi = 0; bi < 16; ++bi)
        part[hh][b0 + bi][lane] = acc[bi];         // lanes consecutive: free
    __syncthreads();

    // ---- uniform combine: each wave handles 4 b ----
    const float b2v = b2[0];
#pragma unroll
    for (int q = 0; q < 4; ++q) {
        const int b = wave * 4 + q;
        const float r = part[0][b][lane] + part[1][b][lane]
                      + part[2][b][lane] + part[3][b][lane];
        out[b * Oo + o0 + lane] = r + SA2w[b] + b2v;   // coalesced 256B
    }
}

extern "C" void kernel_launch(void* const* d_in, const int* in_sizes, int n_in,
                              void* d_out, int out_size, void* d_ws, size_t ws_size,
                              hipStream_t stream) {
    (void)in_sizes; (void)n_in; (void)out_size; (void)ws_size;
    const float* z   = (const float*)d_in[0];   // (64,32)
    const float* fe  = (const float*)d_in[1];   // (16384,32)
    const float* fb  = (const float*)d_in[2];   // (16384,1)
    const float* Wz  = (const float*)d_in[3];   // (32,128)
    const float* bz  = (const float*)d_in[4];   // (128,)
    const float* W1  = (const float*)d_in[5];   // (161,128)
    const float* b1  = (const float*)d_in[6];   // (128,)
    const float* W2  = (const float*)d_in[7];   // (128,1)
    const float* b2  = (const float*)d_in[8];   // (1,)
    float* out  = (float*)d_out;                // (64,16384)
    float* A    = (float*)d_ws;                 // 64*128 floats
    float* SA2w = A + Bb * Hh;                  // 64 floats

    prep_kernel<<<Bb / 2, 256, 0, stream>>>(z, Wz, bz, W1, W2, A, SA2w);
    main_kernel<<<Oo / TOo, NT, 0, stream>>>(A, SA2w, fe, fb, W1, b1, W2, b2, out);
}